// Round 7
// baseline (343.009 us; speedup 1.0000x reference)
//
#include <hip/hip_runtime.h>

#define L 256
#define BATCH 512
#define CIN 32
#define RNNIN 64
#define HIDN 128
#define OUTN 512

typedef float v2 __attribute__((ext_vector_type(2)));

// ws layout (bytes):
//   Wc     @ 0         (16384)    Wc[j*32+c] = sum_m W_ih[j][m]*W_in[m][c]
//   bpre   @ 16384     (512)      b_ih + b_hh + W_ih@b_in
//   hs     @ 32768     (33554432) bf16 hs[t*65536 + b*128 + j]
//   pooled @ 33587200  (262144)   fp32

__global__ __launch_bounds__(128) void prep_kernel(
    const float* __restrict__ W_in, const float* __restrict__ b_in,
    const float* __restrict__ W_ih, const float* __restrict__ b_ih,
    const float* __restrict__ b_hh,
    float* __restrict__ Wc, float* __restrict__ bpre)
{
    const int j = threadIdx.x;
    float acc[CIN];
#pragma unroll
    for (int c = 0; c < CIN; ++c) acc[c] = 0.f;
    float bs = b_ih[j] + b_hh[j];
    for (int m = 0; m < RNNIN; ++m) {
        float w = W_ih[j * RNNIN + m];
        bs += w * b_in[m];
#pragma unroll
        for (int c = 0; c < CIN; ++c) acc[c] += w * W_in[m * CIN + c];
    }
#pragma unroll
    for (int c = 0; c < CIN; ++c) Wc[j * CIN + c] = acc[c];
    bpre[j] = bs;
}

__device__ __forceinline__ float rdlane(float v, int lane) {
    return __int_as_float(__builtin_amdgcn_readlane(__float_as_int(v), lane));
}

// RNN: 512 blocks (1/batch-row) x 256 threads (4 waves) -> 2 blocks/CU, 2 waves/SIMD.
// Wave w owns k-slice [32w,32w+32) of h and x-ch [8w,8w+8). Lane l owns the
// output pair {2l, 2l+1}. Each step:
//   1. h operands via v_readlane from hcur (every wave holds FULL h in lane
//      registers) -> sgpr-pair operands for v_pk_fma_f32. ZERO LDS reads for h.
//   2. x via 2 broadcast ds_read_b128 from the staged x row.
//   3. k-partial exchange: 1 ds_write_b64 + raw s_barrier (lgkmcnt-only wait
//      0xC07F -- does NOT drain the outstanding hs global stores, unlike
//      __syncthreads) + 4 b64 reads, double-buffered -> ONE barrier/step.
//   4. Weights (40 v2 = 80 VGPR/lane) pinned via asm "+v" -- the compiler has
//      refused VGPR residency 4 rounds straight (AGPR parking, VGPR_Count=64).
__global__ __launch_bounds__(256, 2) void rnn_kernel(
    const float* __restrict__ x, const float* __restrict__ h0,
    const float* __restrict__ Whh, const float* __restrict__ Wc,
    const float* __restrict__ bpre, unsigned short* __restrict__ hs)
{
    const int tid  = threadIdx.x;
    const int lane = tid & 63;
    const int w    = tid >> 6;         // wave id 0..3
    const int b    = blockIdx.x;
    const int j0   = 2 * lane, j1 = j0 + 1;
    const int lw   = 16 * w;           // readlane base

    __shared__ float xlds[L][36];      // 36 KB (pad 36: 16B-aligned rows)
    __shared__ v2 part[2][4][64];      // 4 KB partial exchange, double-buffered

    // ---- weights: j0/j1 rows over this wave's k-slice, as pk pairs ----
    v2 wh0[16], wh1[16], wx0[4], wx1[4];
#pragma unroll
    for (int i = 0; i < 16; ++i) {
        wh0[i] = *(const v2*)(Whh + j0 * HIDN + 32 * w + 2 * i);
        wh1[i] = *(const v2*)(Whh + j1 * HIDN + 32 * w + 2 * i);
    }
#pragma unroll
    for (int i = 0; i < 4; ++i) {
        wx0[i] = *(const v2*)(Wc + j0 * CIN + 8 * w + 2 * i);
        wx1[i] = *(const v2*)(Wc + j1 * CIN + 8 * w + 2 * i);
    }
    const float bp0 = bpre[j0], bp1 = bpre[j1];
    // Pin to arch VGPRs: opaque to rematerialization/AGPR parking.
#pragma unroll
    for (int i = 0; i < 16; ++i) {
        asm volatile("" : "+v"(wh0[i].x), "+v"(wh0[i].y));
        asm volatile("" : "+v"(wh1[i].x), "+v"(wh1[i].y));
    }
#pragma unroll
    for (int i = 0; i < 4; ++i) {
        asm volatile("" : "+v"(wx0[i].x), "+v"(wx0[i].y));
        asm volatile("" : "+v"(wx1[i].x), "+v"(wx1[i].y));
    }

    // ---- stage x (32 KB) into LDS [t][c] ----
    const float4* xg = (const float4*)(x + (size_t)b * (CIN * L));
#pragma unroll
    for (int it = 0; it < 8; ++it) {
        int i = tid + it * 256;        // float4 index in [0,2048)
        float4 v = xg[i];
        int c = i >> 6;
        int t0 = (i & 63) * 4;
        xlds[t0 + 0][c] = v.x; xlds[t0 + 1][c] = v.y;
        xlds[t0 + 2][c] = v.z; xlds[t0 + 3][c] = v.w;
    }
    v2 hcur = *(const v2*)(h0 + b * HIDN + j0);   // full h in lane regs (all waves)
    __syncthreads();

    unsigned short* hsb = hs + (size_t)b * HIDN;

    auto step = [&](const int p, const int t) {
        // x part: 2 broadcast b128 reads
        const float* xrow = &xlds[t][8 * w];
        float4 xa = *(const float4*)(xrow);
        float4 xb = *(const float4*)(xrow + 4);
        v2 acc0 = wx0[0] * (v2){xa.x, xa.y};
        v2 acc1 = wx1[0] * (v2){xa.x, xa.y};
        v2 acc2 = wx0[2] * (v2){xb.x, xb.y};
        v2 acc3 = wx1[2] * (v2){xb.x, xb.y};
        acc0 += wx0[1] * (v2){xa.z, xa.w};
        acc1 += wx1[1] * (v2){xa.z, xa.w};
        acc2 += wx0[3] * (v2){xb.z, xb.w};
        acc3 += wx1[3] * (v2){xb.z, xb.w};
        // h part: readlane broadcast -> sgpr-pair pk_fma (no LDS)
#pragma unroll
        for (int i = 0; i < 8; ++i) {
            v2 hp = { rdlane(hcur.x, lw + i), rdlane(hcur.y, lw + i) };
            acc0 += wh0[i] * hp;
            acc1 += wh1[i] * hp;
        }
#pragma unroll
        for (int i = 8; i < 16; ++i) {
            v2 hp = { rdlane(hcur.x, lw + i), rdlane(hcur.y, lw + i) };
            acc2 += wh0[i] * hp;
            acc3 += wh1[i] * hp;
        }
        v2 s01 = acc0 + acc2;          // j0
        v2 s23 = acc1 + acc3;          // j1
        part[p][w][lane] = (v2){s01.x + s01.y, s23.x + s23.y};

        __builtin_amdgcn_s_waitcnt(0xC07F);   // lgkmcnt(0) only — skip vmcnt drain
        __builtin_amdgcn_s_barrier();

        v2 p0 = part[p][0][lane], p1 = part[p][1][lane];
        v2 p2 = part[p][2][lane], p3 = part[p][3][lane];
        v2 tot = (p0 + p1) + (p2 + p3);
        float pre0 = tot.x + bp0, pre1 = tot.y + bp1;
        // tanh(z) = 1 - 2/(exp(2z)+1)
        float e0 = __expf(2.f * pre0);
        float e1 = __expf(2.f * pre1);
        hcur.x = 1.f - 2.f * __builtin_amdgcn_rcpf(e0 + 1.f);
        hcur.y = 1.f - 2.f * __builtin_amdgcn_rcpf(e1 + 1.f);

        if (w == 0) {                  // hs store (bf16 RNE), coalesced b32/lane
            unsigned ua = __float_as_uint(hcur.x), ub = __float_as_uint(hcur.y);
            ua = (ua + 0x7fffu + ((ua >> 16) & 1u)) >> 16;
            ub = (ub + 0x7fffu + ((ub >> 16) & 1u)) >> 16;
            *(unsigned*)(hsb + (size_t)t * (BATCH * HIDN) + j0) = ua | (ub << 16);
        }
        // no 2nd barrier: next step writes part[p^1]; hcur is wave-local.
    };

    for (int t = 0; t < L; t += 2) {
        step(0, t);
        step(1, t + 1);
    }
}

// Upsample 16x16 -> 32x32 (align_corners) + hardswish + mean, fused. bf16 in.
__global__ __launch_bounds__(256) void pool_kernel(
    const unsigned short* __restrict__ hs, float* __restrict__ pooled)
{
    const int b = blockIdx.x >> 2;
    const int j0 = (blockIdx.x & 3) * 32;
    __shared__ float m[L][32];
    for (int i = threadIdx.x; i < L * 8; i += 256) {
        int jo4 = i & 7, t = i >> 3;
        ushort4 v = *(const ushort4*)(hs + (size_t)t * (BATCH * HIDN) + b * HIDN + j0 + jo4 * 4);
        m[t][jo4 * 4 + 0] = __uint_as_float((unsigned)v.x << 16);
        m[t][jo4 * 4 + 1] = __uint_as_float((unsigned)v.y << 16);
        m[t][jo4 * 4 + 2] = __uint_as_float((unsigned)v.z << 16);
        m[t][jo4 * 4 + 3] = __uint_as_float((unsigned)v.w << 16);
    }
    __syncthreads();
    const int jo = threadIdx.x & 31;
    const int sub = threadIdx.x >> 5;
    float acc = 0.f;
#pragma unroll 4
    for (int p = sub; p < 1024; p += 8) {
        int oy = p >> 5, ox = p & 31;
        float ysf = oy * (15.f / 31.f);
        int y0 = (int)ysf; float wy = ysf - (float)y0; int y1 = min(y0 + 1, 15);
        float xsf = ox * (15.f / 31.f);
        int x0 = (int)xsf; float wx = xsf - (float)x0; int x1 = min(x0 + 1, 15);
        float v00 = m[y0 * 16 + x0][jo], v01 = m[y0 * 16 + x1][jo];
        float v10 = m[y1 * 16 + x0][jo], v11 = m[y1 * 16 + x1][jo];
        float v0 = v00 + wx * (v01 - v00);
        float v1 = v10 + wx * (v11 - v10);
        float v = v0 + wy * (v1 - v0);
        float t6 = fminf(fmaxf(v + 3.f, 0.f), 6.f);
        acc += v * t6;
    }
    __shared__ float ps[8][32];
    ps[sub][jo] = acc;
    __syncthreads();
    if (threadIdx.x < 32) {
        float sum = 0.f;
#pragma unroll
        for (int u = 0; u < 8; ++u) sum += ps[u][threadIdx.x];
        pooled[b * HIDN + j0 + threadIdx.x] = sum * (1.f / 6144.f);
    }
}

__global__ __launch_bounds__(256) void out_kernel(
    const float* __restrict__ pooled, const float* __restrict__ W_out,
    const float* __restrict__ b_out, float* __restrict__ out)
{
    const int b = blockIdx.x;
    __shared__ float pv[HIDN];
    if (threadIdx.x < HIDN) pv[threadIdx.x] = pooled[b * HIDN + threadIdx.x];
    __syncthreads();
    for (int o = threadIdx.x; o < OUTN; o += 256) {
        float acc = b_out[o];
#pragma unroll 8
        for (int k = 0; k < HIDN; k += 4) {
            float4 w = *(const float4*)(W_out + o * HIDN + k);
            acc += w.x * pv[k] + w.y * pv[k + 1] + w.z * pv[k + 2] + w.w * pv[k + 3];
        }
        out[b * OUTN + o] = acc;
    }
}

extern "C" void kernel_launch(void* const* d_in, const int* in_sizes, int n_in,
                              void* d_out, int out_size, void* d_ws, size_t ws_size,
                              hipStream_t stream)
{
    const float* x     = (const float*)d_in[0];
    const float* h0    = (const float*)d_in[1];
    const float* W_in  = (const float*)d_in[2];
    const float* b_in  = (const float*)d_in[3];
    const float* W_ih  = (const float*)d_in[4];
    const float* b_ih  = (const float*)d_in[5];
    const float* W_hh  = (const float*)d_in[6];
    const float* b_hh  = (const float*)d_in[7];
    const float* W_out = (const float*)d_in[8];
    const float* b_out = (const float*)d_in[9];
    float* out = (float*)d_out;

    char* wsb = (char*)d_ws;
    float* Wc          = (float*)(wsb);                  // 16384 B
    float* bpre        = (float*)(wsb + 16384);          // 512 B
    unsigned short* hs = (unsigned short*)(wsb + 32768); // 32 MB bf16
    float* pooled      = (float*)(wsb + 33587200);       // 256 KB

    prep_kernel<<<1, 128, 0, stream>>>(W_in, b_in, W_ih, b_ih, b_hh, Wc, bpre);
    rnn_kernel<<<512, 256, 0, stream>>>(x, h0, W_hh, Wc, bpre, hs);
    pool_kernel<<<2048, 256, 0, stream>>>(hs, pooled);
    out_kernel<<<512, 256, 0, stream>>>(pooled, W_out, b_out, out);
}

// Round 8
// 331.333 us; speedup vs baseline: 1.0352x; 1.0352x over previous
//
#include <hip/hip_runtime.h>
#include <hip/hip_bf16.h>

#define L 256
#define BATCH 512
#define CIN 32
#define HIDN 128
#define OUTN 512

typedef __attribute__((ext_vector_type(8))) short bf16x8;
typedef __attribute__((ext_vector_type(4))) float f32x4;

#define MFMA(a, b, c) __builtin_amdgcn_mfma_f32_16x16x32_bf16(a, b, c, 0, 0, 0)

static __device__ __forceinline__ unsigned short bf16_rne(float f) {
    unsigned u = __float_as_uint(f);
    return (unsigned short)((u + 0x7fffu + ((u >> 16) & 1u)) >> 16);
}
static __device__ __forceinline__ unsigned b2u(__hip_bfloat162 v) {
    unsigned u; __builtin_memcpy(&u, &v, 4); return u;
}

// ws layout (bytes):
//   Wh   @ 0        (32768)   bf16 hi of W_hh [j][k]
//   Wl   @ 32768    (32768)   bf16 lo residual
//   Wch  @ 65536    (8192)    bf16 hi of Wc = W_ih@W_in [j][c]
//   Wcl  @ 73728    (8192)
//   bpre @ 81920    (512)     fp32 b_ih + b_hh + W_ih@b_in
//   xTh  @ 98304    (8388608) bf16 hi of x_seq^T: [b][t][c]
//   xTl  @ 8486912  (8388608)
//   hs   @ 16875520 (33554432) bf16 hs[t*65536 + b*128 + j]
//   pooled @ 50429952 (262144) fp32

__global__ __launch_bounds__(256) void prep_kernel(
    const float* __restrict__ W_in, const float* __restrict__ b_in,
    const float* __restrict__ W_ih, const float* __restrict__ b_ih,
    const float* __restrict__ b_hh, const float* __restrict__ Whh,
    unsigned short* __restrict__ Wh, unsigned short* __restrict__ Wl,
    unsigned short* __restrict__ Wch, unsigned short* __restrict__ Wcl,
    float* __restrict__ bpre)
{
    const int tid = threadIdx.x;
    if (tid < 128) {
        const int j = tid;
        float acc[CIN];
#pragma unroll
        for (int c = 0; c < CIN; ++c) acc[c] = 0.f;
        float bs = b_ih[j] + b_hh[j];
        for (int m = 0; m < 64; ++m) {
            float w = W_ih[j * 64 + m];
            bs += w * b_in[m];
#pragma unroll
            for (int c = 0; c < CIN; ++c) acc[c] += w * W_in[m * CIN + c];
        }
        bpre[j] = bs;
#pragma unroll
        for (int c = 0; c < CIN; ++c) {
            float v = acc[c];
            unsigned short h = bf16_rne(v);
            float hf = __uint_as_float((unsigned)h << 16);
            Wch[j * CIN + c] = h;
            Wcl[j * CIN + c] = bf16_rne(v - hf);
        }
    } else {
        const int j = tid - 128;
        for (int k = 0; k < HIDN; ++k) {
            float v = Whh[j * HIDN + k];
            unsigned short h = bf16_rne(v);
            float hf = __uint_as_float((unsigned)h << 16);
            Wh[j * HIDN + k] = h;
            Wl[j * HIDN + k] = bf16_rne(v - hf);
        }
    }
}

// x[b][c][t] -> xTh/xTl[b][t][c] (split bf16). 512 blocks, 256 thr (thread = t).
__global__ __launch_bounds__(256) void xt_kernel(
    const float* __restrict__ x,
    unsigned short* __restrict__ xTh, unsigned short* __restrict__ xTl)
{
    const int b = blockIdx.x, tid = threadIdx.x;
    __shared__ float xl[L][36];
    const float4* xg = (const float4*)(x + (size_t)b * (CIN * L));
#pragma unroll
    for (int it = 0; it < 8; ++it) {
        int i = tid + it * 256;
        float4 v = xg[i];
        int c = i >> 6, t0 = (i & 63) * 4;
        xl[t0 + 0][c] = v.x; xl[t0 + 1][c] = v.y;
        xl[t0 + 2][c] = v.z; xl[t0 + 3][c] = v.w;
    }
    __syncthreads();
    const int t = tid;
    unsigned short* oh = xTh + ((size_t)b * L + t) * CIN;
    unsigned short* ol = xTl + ((size_t)b * L + t) * CIN;
#pragma unroll
    for (int p = 0; p < 4; ++p) {
        unsigned hv[8], lv[8];
#pragma unroll
        for (int i = 0; i < 8; ++i) {
            float v = xl[t][p * 8 + i];
            unsigned short h = bf16_rne(v);
            float hf = __uint_as_float((unsigned)h << 16);
            hv[i] = h; lv[i] = bf16_rne(v - hf);
        }
        uint4 ph = { hv[0] | (hv[1] << 16), hv[2] | (hv[3] << 16),
                     hv[4] | (hv[5] << 16), hv[6] | (hv[7] << 16) };
        uint4 pl = { lv[0] | (lv[1] << 16), lv[2] | (lv[3] << 16),
                     lv[4] | (lv[5] << 16), lv[6] | (lv[7] << 16) };
        *(uint4*)(oh + p * 8) = ph;
        *(uint4*)(ol + p * 8) = pl;
    }
}

// MFMA RNN. 32 blocks (16 batch rows each) x 256 thr (4 waves, 1/SIMD).
// Wave w owns j-slice [32w,32w+32) as 2 16x16 tiles. Step:
//   D[j][b] = (Wh+Wl)(hh+hl) + (Wch+Wcl)(xh+xl) + bpre  (3-term split each)
// B-frags (h) from 16B-granule-swizzled LDS planes (c ^= n&7: <=2-way banks);
// A-frags (W) + bias static in regs/AGPRs (MFMA reads AGPR operands natively
// -- ends the VGPR-residency war of R3-R6). C/D map (m89): col=lane&15=batch,
// row=quad*4+reg = 4 consecutive j -> b64 LDS writes + register-direct hs.
// One raw s_barrier/step with lgkm-only wait (hs stores stay in flight).
__global__ __launch_bounds__(256, 1) void rnn_kernel(
    const float* __restrict__ h0,
    const unsigned short* __restrict__ Wh, const unsigned short* __restrict__ Wl,
    const unsigned short* __restrict__ Wch, const unsigned short* __restrict__ Wcl,
    const float* __restrict__ bpre,
    const unsigned short* __restrict__ xTh, const unsigned short* __restrict__ xTl,
    unsigned short* __restrict__ hs)
{
    const int tid = threadIdx.x;
    const int bb = blockIdx.x;
    const int lane = tid & 63;
    const int w = tid >> 6;
    const int n = lane & 15;      // batch col within block
    const int q = lane >> 4;      // quad

    __shared__ unsigned short hbuf[2][2][16][HIDN];  // [dbuf][hi/lo][n][k] 16KB

    // ---- h0 -> split planes, dbuf 0 ----
    {
        const int ni = tid >> 4, ci = tid & 15;  // granule ci = 8 k-values
        const float4* src = (const float4*)(h0 + ((size_t)bb * 16 + ni) * HIDN + ci * 8);
        float4 a = src[0], b4 = src[1];
        float vv[8] = {a.x, a.y, a.z, a.w, b4.x, b4.y, b4.z, b4.w};
        unsigned hh[8], hl[8];
#pragma unroll
        for (int i = 0; i < 8; ++i) {
            unsigned short h = bf16_rne(vv[i]);
            float hf = __uint_as_float((unsigned)h << 16);
            hh[i] = h; hl[i] = bf16_rne(vv[i] - hf);
        }
        const int cs = ci ^ (ni & 7);
        *(uint4*)&hbuf[0][0][ni][cs * 8] = (uint4){ hh[0] | (hh[1] << 16), hh[2] | (hh[3] << 16),
                                                    hh[4] | (hh[5] << 16), hh[6] | (hh[7] << 16) };
        *(uint4*)&hbuf[0][1][ni][cs * 8] = (uint4){ hl[0] | (hl[1] << 16), hl[2] | (hl[3] << 16),
                                                    hl[4] | (hl[5] << 16), hl[6] | (hl[7] << 16) };
    }

    // ---- static A-frags + bias ----
    bf16x8 Ah[2][4], Al[2][4], Axh[2], Axl[2];
    f32x4 bp[2];
#pragma unroll
    for (int T = 0; T < 2; ++T) {
        const int jr = w * 32 + T * 16 + n;   // A row = lane&15
#pragma unroll
        for (int kc = 0; kc < 4; ++kc) {
            Ah[T][kc] = *(const bf16x8*)(Wh + jr * HIDN + kc * 32 + q * 8);
            Al[T][kc] = *(const bf16x8*)(Wl + jr * HIDN + kc * 32 + q * 8);
        }
        Axh[T] = *(const bf16x8*)(Wch + jr * CIN + q * 8);
        Axl[T] = *(const bf16x8*)(Wcl + jr * CIN + q * 8);
        float4 bv = *(const float4*)(bpre + w * 32 + T * 16 + q * 4);
        bp[T] = (f32x4){bv.x, bv.y, bv.z, bv.w};
    }

    // x gather (per-lane strided; 16x64B segments; prefetched 1 step ahead)
    const unsigned short* xph = xTh + (((size_t)bb * 16 + n) * L) * CIN + q * 8;
    const unsigned short* xpl = xTl + (((size_t)bb * 16 + n) * L) * CIN + q * 8;
    bf16x8 xh = *(const bf16x8*)xph;
    bf16x8 xlo = *(const bf16x8*)xpl;

    __syncthreads();

    unsigned short* hsp = hs + ((size_t)bb * 16 + n) * HIDN + w * 32 + q * 4;

    for (int t = 0; t < L; ++t) {
        const int p = t & 1;
        // B-frags: B[k=q*8+i + 32kc][n]
        bf16x8 Bh[4], Bl[4];
#pragma unroll
        for (int kc = 0; kc < 4; ++kc) {
            const int cs = (kc * 4 + q) ^ (n & 7);
            Bh[kc] = *(const bf16x8*)&hbuf[p][0][n][cs * 8];
            Bl[kc] = *(const bf16x8*)&hbuf[p][1][n][cs * 8];
        }
        // prefetch next x
        const int tn = (t + 1 < L) ? t + 1 : t;
        bf16x8 xh_n = *(const bf16x8*)(xph + (size_t)tn * CIN);
        bf16x8 xl_n = *(const bf16x8*)(xpl + (size_t)tn * CIN);

        // 30 MFMA in 4 chains (a0,b0 tile0; a1,b1 tile1)
        f32x4 a0 = bp[0], a1 = bp[1];
        f32x4 b0 = (f32x4){0.f, 0.f, 0.f, 0.f}, b1 = b0;
#pragma unroll
        for (int kc = 0; kc < 2; ++kc) {
            a0 = MFMA(Ah[0][kc], Bh[kc], a0);      a1 = MFMA(Ah[1][kc], Bh[kc], a1);
            b0 = MFMA(Ah[0][kc + 2], Bh[kc + 2], b0); b1 = MFMA(Ah[1][kc + 2], Bh[kc + 2], b1);
            a0 = MFMA(Al[0][kc], Bh[kc], a0);      a1 = MFMA(Al[1][kc], Bh[kc], a1);
            b0 = MFMA(Al[0][kc + 2], Bh[kc + 2], b0); b1 = MFMA(Al[1][kc + 2], Bh[kc + 2], b1);
            a0 = MFMA(Ah[0][kc], Bl[kc], a0);      a1 = MFMA(Ah[1][kc], Bl[kc], a1);
            b0 = MFMA(Ah[0][kc + 2], Bl[kc + 2], b0); b1 = MFMA(Ah[1][kc + 2], Bl[kc + 2], b1);
        }
        a0 = MFMA(Axh[0], xh, a0);   a1 = MFMA(Axh[1], xh, a1);
        b0 = MFMA(Axl[0], xh, b0);   b1 = MFMA(Axl[1], xh, b1);
        a0 = MFMA(Axh[0], xlo, a0);  a1 = MFMA(Axh[1], xlo, a1);

        // epilogue per tile: tanh, split, LDS write (swizzled), hs store
#pragma unroll
        for (int T = 0; T < 2; ++T) {
            f32x4 acc = T ? (a1 + b1) : (a0 + b0);
            float hv[4];
#pragma unroll
            for (int r = 0; r < 4; ++r) {
                float e = __expf(2.f * acc[r]);
                hv[r] = 1.f - 2.f * __builtin_amdgcn_rcpf(e + 1.f);
            }
            unsigned u01 = b2u(__float22bfloat162_rn(make_float2(hv[0], hv[1])));
            unsigned u23 = b2u(__float22bfloat162_rn(make_float2(hv[2], hv[3])));
            float r0 = hv[0] - __uint_as_float(u01 << 16);
            float r1 = hv[1] - __uint_as_float(u01 & 0xffff0000u);
            float r2 = hv[2] - __uint_as_float(u23 << 16);
            float r3 = hv[3] - __uint_as_float(u23 & 0xffff0000u);
            unsigned l01 = b2u(__float22bfloat162_rn(make_float2(r0, r1)));
            unsigned l23 = b2u(__float22bfloat162_rn(make_float2(r2, r3)));

            const int cgr = w * 4 + T * 2 + (q >> 1);   // 16B granule of j0=w*32+T*16+q*4
            const int cs = cgr ^ (n & 7);
            const int half = q & 1;
            *(uint2*)&hbuf[p ^ 1][0][n][cs * 8 + half * 4] = (uint2){u01, u23};
            *(uint2*)&hbuf[p ^ 1][1][n][cs * 8 + half * 4] = (uint2){l01, l23};
            *(uint2*)(hsp + (size_t)t * (BATCH * HIDN) + T * 16) = (uint2){u01, u23};
        }

        __builtin_amdgcn_s_waitcnt(0xC07F);  // lgkmcnt(0) only; hs stores stay in flight
        __builtin_amdgcn_s_barrier();
        xh = xh_n; xlo = xl_n;
    }
}

// Upsample 16x16 -> 32x32 (align_corners) + hardswish + mean, fused. bf16 in.
__global__ __launch_bounds__(256) void pool_kernel(
    const unsigned short* __restrict__ hs, float* __restrict__ pooled)
{
    const int b = blockIdx.x >> 2;
    const int j0 = (blockIdx.x & 3) * 32;
    __shared__ float m[L][32];
    for (int i = threadIdx.x; i < L * 8; i += 256) {
        int jo4 = i & 7, t = i >> 3;
        ushort4 v = *(const ushort4*)(hs + (size_t)t * (BATCH * HIDN) + b * HIDN + j0 + jo4 * 4);
        m[t][jo4 * 4 + 0] = __uint_as_float((unsigned)v.x << 16);
        m[t][jo4 * 4 + 1] = __uint_as_float((unsigned)v.y << 16);
        m[t][jo4 * 4 + 2] = __uint_as_float((unsigned)v.z << 16);
        m[t][jo4 * 4 + 3] = __uint_as_float((unsigned)v.w << 16);
    }
    __syncthreads();
    const int jo = threadIdx.x & 31;
    const int sub = threadIdx.x >> 5;
    float acc = 0.f;
#pragma unroll 4
    for (int p = sub; p < 1024; p += 8) {
        int oy = p >> 5, ox = p & 31;
        float ysf = oy * (15.f / 31.f);
        int y0 = (int)ysf; float wy = ysf - (float)y0; int y1 = min(y0 + 1, 15);
        float xsf = ox * (15.f / 31.f);
        int x0 = (int)xsf; float wx = xsf - (float)x0; int x1 = min(x0 + 1, 15);
        float v00 = m[y0 * 16 + x0][jo], v01 = m[y0 * 16 + x1][jo];
        float v10 = m[y1 * 16 + x0][jo], v11 = m[y1 * 16 + x1][jo];
        float v0 = v00 + wx * (v01 - v00);
        float v1 = v10 + wx * (v11 - v10);
        float v = v0 + wy * (v1 - v0);
        float t6 = fminf(fmaxf(v + 3.f, 0.f), 6.f);
        acc += v * t6;
    }
    __shared__ float ps[8][32];
    ps[sub][jo] = acc;
    __syncthreads();
    if (threadIdx.x < 32) {
        float sum = 0.f;
#pragma unroll
        for (int u = 0; u < 8; ++u) sum += ps[u][threadIdx.x];
        pooled[b * HIDN + j0 + threadIdx.x] = sum * (1.f / 6144.f);
    }
}

__global__ __launch_bounds__(256) void out_kernel(
    const float* __restrict__ pooled, const float* __restrict__ W_out,
    const float* __restrict__ b_out, float* __restrict__ out)
{
    const int b = blockIdx.x;
    __shared__ float pv[HIDN];
    if (threadIdx.x < HIDN) pv[threadIdx.x] = pooled[b * HIDN + threadIdx.x];
    __syncthreads();
    for (int o = threadIdx.x; o < OUTN; o += 256) {
        float acc = b_out[o];
#pragma unroll 8
        for (int k = 0; k < HIDN; k += 4) {
            float4 w = *(const float4*)(W_out + o * HIDN + k);
            acc += w.x * pv[k] + w.y * pv[k + 1] + w.z * pv[k + 2] + w.w * pv[k + 3];
        }
        out[b * OUTN + o] = acc;
    }
}

extern "C" void kernel_launch(void* const* d_in, const int* in_sizes, int n_in,
                              void* d_out, int out_size, void* d_ws, size_t ws_size,
                              hipStream_t stream)
{
    const float* x     = (const float*)d_in[0];
    const float* h0    = (const float*)d_in[1];
    const float* W_in  = (const float*)d_in[2];
    const float* b_in  = (const float*)d_in[3];
    const float* W_ih  = (const float*)d_in[4];
    const float* b_ih  = (const float*)d_in[5];
    const float* W_hh  = (const float*)d_in[6];
    const float* b_hh  = (const float*)d_in[7];
    const float* W_out = (const float*)d_in[8];
    const float* b_out = (const float*)d_in[9];
    float* out = (float*)d_out;

    char* wsb = (char*)d_ws;
    unsigned short* Wh  = (unsigned short*)(wsb);
    unsigned short* Wl  = (unsigned short*)(wsb + 32768);
    unsigned short* Wch = (unsigned short*)(wsb + 65536);
    unsigned short* Wcl = (unsigned short*)(wsb + 73728);
    float* bpre         = (float*)(wsb + 81920);
    unsigned short* xTh = (unsigned short*)(wsb + 98304);
    unsigned short* xTl = (unsigned short*)(wsb + 8486912);
    unsigned short* hsb = (unsigned short*)(wsb + 16875520);
    float* pooled       = (float*)(wsb + 50429952);

    prep_kernel<<<1, 256, 0, stream>>>(W_in, b_in, W_ih, b_ih, b_hh, W_hh,
                                       Wh, Wl, Wch, Wcl, bpre);
    xt_kernel<<<512, 256, 0, stream>>>(x, xTh, xTl);
    rnn_kernel<<<32, 256, 0, stream>>>(h0, Wh, Wl, Wch, Wcl, bpre, xTh, xTl, hsb);
    pool_kernel<<<2048, 256, 0, stream>>>(hsb, pooled);
    out_kernel<<<512, 256, 0, stream>>>(pooled, W_out, b_out, out);
}

// Round 9
// 283.676 us; speedup vs baseline: 1.2092x; 1.1680x over previous
//
#include <hip/hip_runtime.h>

#define L 256
#define BATCH 512
#define CIN 32
#define HIDN 128
#define OUTN 512

typedef _Float16 f16x8 __attribute__((ext_vector_type(8)));
typedef float f32x4 __attribute__((ext_vector_type(4)));

#define MFMA16(a, b, c) __builtin_amdgcn_mfma_f32_16x16x32_f16(a, b, c, 0, 0, 0)

static __device__ __forceinline__ unsigned short f16b(_Float16 h) {
    unsigned short u; __builtin_memcpy(&u, &h, 2); return u;
}

// ws layout (bytes):
//   Wh   @ 0      (32768)  fp16 hi of W_hh [j][k]
//   Wl   @ 32768  (32768)  fp16 lo residual (W captured to 22 bits: W-error is
//                          systematic across 256 steps, must be ~exact)
//   Wch  @ 65536  (8192)   fp16 hi of Wc = W_ih@W_in [j][c]
//   Wcl  @ 73728  (8192)
//   bpre @ 81920  (512)    fp32 b_ih + b_hh + W_ih@b_in
//   hs   @ 98304  (33554432) fp16 hs[t*65536 + b*128 + j]
//   pooled @ 33652736 (262144) fp32

__global__ __launch_bounds__(256) void prep_kernel(
    const float* __restrict__ W_in, const float* __restrict__ b_in,
    const float* __restrict__ W_ih, const float* __restrict__ b_ih,
    const float* __restrict__ b_hh, const float* __restrict__ Whh,
    unsigned short* __restrict__ Wh, unsigned short* __restrict__ Wl,
    unsigned short* __restrict__ Wch, unsigned short* __restrict__ Wcl,
    float* __restrict__ bpre)
{
    const int tid = threadIdx.x;
    __shared__ float win[64 * CIN];              // 8 KB W_in stage
    for (int i = tid; i < 64 * CIN; i += 256) win[i] = W_in[i];
    __syncthreads();
    if (tid < 128) {
        const int j = tid;
        float acc[CIN];
#pragma unroll
        for (int c = 0; c < CIN; ++c) acc[c] = 0.f;
        float bs = b_ih[j] + b_hh[j];
        for (int m = 0; m < 64; ++m) {
            float w = W_ih[j * 64 + m];
            bs += w * b_in[m];
#pragma unroll
            for (int c = 0; c < CIN; ++c) acc[c] += w * win[m * CIN + c];
        }
        bpre[j] = bs;
#pragma unroll
        for (int c = 0; c < CIN; ++c) {
            _Float16 h = (_Float16)acc[c];
            _Float16 l = (_Float16)(acc[c] - (float)h);
            Wch[j * CIN + c] = f16b(h);
            Wcl[j * CIN + c] = f16b(l);
        }
    } else {
        const int j = tid - 128;
        for (int k = 0; k < HIDN; k += 4) {
            float4 v = *(const float4*)(Whh + j * HIDN + k);
            float vv[4] = {v.x, v.y, v.z, v.w};
#pragma unroll
            for (int u = 0; u < 4; ++u) {
                _Float16 h = (_Float16)vv[u];
                _Float16 l = (_Float16)(vv[u] - (float)h);
                Wh[j * HIDN + k + u] = f16b(h);
                Wl[j * HIDN + k + u] = f16b(l);
            }
        }
    }
}

// MFMA RNN, fp16 2-term split. 32 blocks (16 batch rows) x 256 thr (4 waves).
// Wave w owns j-slice [32w,32w+32) (2 16x16 tiles), full K=128 itself; the
// barrier only publishes h. Per step per wave: 20 MFMA in 4 chains of 5,
// 4 swizzled b128 h-reads + 1 x-read. x staged fp32->fp16 into LDS in
// 16-step chunks, loads issued a full chunk ahead (no vmcnt in the loop).
// h and hs in fp16: W captured to 22 bits (systematic), h/x to 11 bits
// (fresh per-step noise, random-walk accumulation).
__global__ __launch_bounds__(256, 1) void rnn_kernel(
    const float* __restrict__ x, const float* __restrict__ h0,
    const unsigned short* __restrict__ Wh, const unsigned short* __restrict__ Wl,
    const unsigned short* __restrict__ Wch, const unsigned short* __restrict__ Wcl,
    const float* __restrict__ bpre, unsigned short* __restrict__ hs)
{
    const int tid = threadIdx.x;
    const int bb = blockIdx.x;
    const int lane = tid & 63;
    const int w = tid >> 6;
    const int n = lane & 15;      // batch col
    const int q = lane >> 4;      // quad

    __shared__ unsigned short hbuf[2][16][HIDN];     // 8 KB, 16B-granule swizzle ^(n&7)
    __shared__ unsigned short xc[2][16][16][CIN];    // 32 KB, [chunk][t&15][n][c]

    // ---- A-frags + bias (MFMA reads operands from AGPRs natively) ----
    f16x8 Ah[2][4], Al[2][4], Axh[2], Axl[2];
    f32x4 bp[2];
#pragma unroll
    for (int T = 0; T < 2; ++T) {
        const int jr = w * 32 + T * 16 + n;
#pragma unroll
        for (int kc = 0; kc < 4; ++kc) {
            Ah[T][kc] = *(const f16x8*)(Wh + jr * HIDN + kc * 32 + q * 8);
            Al[T][kc] = *(const f16x8*)(Wl + jr * HIDN + kc * 32 + q * 8);
        }
        Axh[T] = *(const f16x8*)(Wch + jr * CIN + q * 8);
        Axl[T] = *(const f16x8*)(Wcl + jr * CIN + q * 8);
        float4 bv = *(const float4*)(bpre + w * 32 + T * 16 + q * 4);
        bp[T] = (f32x4){bv.x, bv.y, bv.z, bv.w};
    }

    // ---- h0 -> fp16 plane, dbuf 0 ----
    {
        const int ni = tid >> 4, gi = tid & 15;      // granule gi = 8 k-values
        const float4* src = (const float4*)(h0 + ((size_t)bb * 16 + ni) * HIDN + gi * 8);
        float4 a = src[0], b4 = src[1];
        float vv[8] = {a.x, a.y, a.z, a.w, b4.x, b4.y, b4.z, b4.w};
        unsigned short o[8];
#pragma unroll
        for (int i = 0; i < 8; ++i) o[i] = f16b((_Float16)vv[i]);
        unsigned short* dst = &hbuf[0][ni][(gi ^ (ni & 7)) * 8];
        *(uint4*)dst = *(uint4*)o;
    }

    // ---- x chunk staging: thread i -> (n=i>>7, c=(i>>2)&31, tq=i&3) ----
    const int sn = tid >> 5, sc = (tid >> 0) ; // placeholder to keep names clear
    float4 xr[8];
    auto issue_chunk = [&](int ci) {
#pragma unroll
        for (int r = 0; r < 8; ++r) {
            int i = tid + r * 256;
            int nn = i >> 7, cc = (i >> 2) & 31, tq = i & 3;
            xr[r] = *(const float4*)(x + (((size_t)bb * 16 + nn) * CIN + cc) * L + ci * 16 + tq * 4);
        }
    };
    auto write_chunk = [&](int buf) {
#pragma unroll
        for (int r = 0; r < 8; ++r) {
            int i = tid + r * 256;
            int nn = i >> 7, cc = (i >> 2) & 31, tq = i & 3;
            float vv[4] = {xr[r].x, xr[r].y, xr[r].z, xr[r].w};
#pragma unroll
            for (int k = 0; k < 4; ++k)
                xc[buf][tq * 4 + k][nn][cc] = f16b((_Float16)vv[k]);
        }
    };
    (void)sn; (void)sc;

    issue_chunk(0);
    write_chunk(0);
    issue_chunk(1);
    __syncthreads();

    unsigned short* hsp = hs + ((size_t)bb * 16 + n) * HIDN + w * 32 + q * 4;

    for (int t = 0; t < L; ++t) {
        const int p = t & 1;
        const int cb = (t >> 4) & 1, tt = t & 15;

        // B-frags: h (4 swizzled b128) + x (1 b128)
        f16x8 Bh[4];
#pragma unroll
        for (int kc = 0; kc < 4; ++kc)
            Bh[kc] = *(const f16x8*)&hbuf[p][n][((4 * kc + q) ^ (n & 7)) * 8];
        f16x8 xB = *(const f16x8*)&xc[cb][tt][n][q * 8];

        // 20 MFMA, 4 chains of 5
        f32x4 aH0 = bp[0], aH1 = bp[1];
        f32x4 aL0 = (f32x4){0.f, 0.f, 0.f, 0.f}, aL1 = aL0;
#pragma unroll
        for (int kc = 0; kc < 4; ++kc) {
            aH0 = MFMA16(Ah[0][kc], Bh[kc], aH0);
            aH1 = MFMA16(Ah[1][kc], Bh[kc], aH1);
            aL0 = MFMA16(Al[0][kc], Bh[kc], aL0);
            aL1 = MFMA16(Al[1][kc], Bh[kc], aL1);
        }
        aH0 = MFMA16(Axh[0], xB, aH0);
        aH1 = MFMA16(Axh[1], xB, aH1);
        aL0 = MFMA16(Axl[0], xB, aL0);
        aL1 = MFMA16(Axl[1], xB, aL1);

        // x chunk rotation (every 16 steps; data loaded 16 steps ago)
        if (tt == 15 && t < L - 16) {
            write_chunk(cb ^ 1);
            if (t < L - 32) issue_chunk((t >> 4) + 2);
        }

        // epilogue: tanh -> fp16 -> hbuf (swizzled) + hs
#pragma unroll
        for (int T = 0; T < 2; ++T) {
            f32x4 acc = T ? (aH1 + aL1) : (aH0 + aL0);
            unsigned short o[4];
#pragma unroll
            for (int r = 0; r < 4; ++r) {
                float e = __expf(2.f * acc[r]);
                float hv = 1.f - 2.f * __builtin_amdgcn_rcpf(e + 1.f);
                o[r] = f16b((_Float16)hv);
            }
            uint2 pk; __builtin_memcpy(&pk, o, 8);
            const int G = (w * 4 + T * 2 + (q >> 1)) ^ (n & 7);
            *(uint2*)&hbuf[p ^ 1][n][G * 8 + (q & 1) * 4] = pk;
            *(uint2*)(hsp + (size_t)t * (BATCH * HIDN) + T * 16) = pk;
        }

        asm volatile("" ::: "memory");
        __builtin_amdgcn_s_waitcnt(0xC07F);  // lgkmcnt(0) only; hs stores stay in flight
        __builtin_amdgcn_s_barrier();
        asm volatile("" ::: "memory");
    }
}

// Upsample 16x16 -> 32x32 (align_corners) + hardswish + mean, fused. fp16 in.
__global__ __launch_bounds__(256) void pool_kernel(
    const unsigned short* __restrict__ hs, float* __restrict__ pooled)
{
    const int b = blockIdx.x >> 2;
    const int j0 = (blockIdx.x & 3) * 32;
    __shared__ float m[L][32];
    for (int i = threadIdx.x; i < L * 8; i += 256) {
        int jo4 = i & 7, t = i >> 3;
        ushort4 v = *(const ushort4*)(hs + (size_t)t * (BATCH * HIDN) + b * HIDN + j0 + jo4 * 4);
        m[t][jo4 * 4 + 0] = (float)*(_Float16*)&v.x;
        m[t][jo4 * 4 + 1] = (float)*(_Float16*)&v.y;
        m[t][jo4 * 4 + 2] = (float)*(_Float16*)&v.z;
        m[t][jo4 * 4 + 3] = (float)*(_Float16*)&v.w;
    }
    __syncthreads();
    const int jo = threadIdx.x & 31;
    const int sub = threadIdx.x >> 5;
    float acc = 0.f;
#pragma unroll 4
    for (int p = sub; p < 1024; p += 8) {
        int oy = p >> 5, ox = p & 31;
        float ysf = oy * (15.f / 31.f);
        int y0 = (int)ysf; float wy = ysf - (float)y0; int y1 = min(y0 + 1, 15);
        float xsf = ox * (15.f / 31.f);
        int x0 = (int)xsf; float wx = xsf - (float)x0; int x1 = min(x0 + 1, 15);
        float v00 = m[y0 * 16 + x0][jo], v01 = m[y0 * 16 + x1][jo];
        float v10 = m[y1 * 16 + x0][jo], v11 = m[y1 * 16 + x1][jo];
        float v0 = v00 + wx * (v01 - v00);
        float v1 = v10 + wx * (v11 - v10);
        float v = v0 + wy * (v1 - v0);
        float t6 = fminf(fmaxf(v + 3.f, 0.f), 6.f);
        acc += v * t6;
    }
    __shared__ float ps[8][32];
    ps[sub][jo] = acc;
    __syncthreads();
    if (threadIdx.x < 32) {
        float sum = 0.f;
#pragma unroll
        for (int u = 0; u < 8; ++u) sum += ps[u][threadIdx.x];
        pooled[b * HIDN + j0 + threadIdx.x] = sum * (1.f / 6144.f);
    }
}

__global__ __launch_bounds__(256) void out_kernel(
    const float* __restrict__ pooled, const float* __restrict__ W_out,
    const float* __restrict__ b_out, float* __restrict__ out)
{
    const int b = blockIdx.x;
    __shared__ float pv[HIDN];
    if (threadIdx.x < HIDN) pv[threadIdx.x] = pooled[b * HIDN + threadIdx.x];
    __syncthreads();
    for (int o = threadIdx.x; o < OUTN; o += 256) {
        float acc = b_out[o];
#pragma unroll 8
        for (int k = 0; k < HIDN; k += 4) {
            float4 wv = *(const float4*)(W_out + o * HIDN + k);
            acc += wv.x * pv[k] + wv.y * pv[k + 1] + wv.z * pv[k + 2] + wv.w * pv[k + 3];
        }
        out[b * OUTN + o] = acc;
    }
}

extern "C" void kernel_launch(void* const* d_in, const int* in_sizes, int n_in,
                              void* d_out, int out_size, void* d_ws, size_t ws_size,
                              hipStream_t stream)
{
    const float* x     = (const float*)d_in[0];
    const float* h0    = (const float*)d_in[1];
    const float* W_in  = (const float*)d_in[2];
    const float* b_in  = (const float*)d_in[3];
    const float* W_ih  = (const float*)d_in[4];
    const float* b_ih  = (const float*)d_in[5];
    const float* W_hh  = (const float*)d_in[6];
    const float* b_hh  = (const float*)d_in[7];
    const float* W_out = (const float*)d_in[8];
    const float* b_out = (const float*)d_in[9];
    float* out = (float*)d_out;

    char* wsb = (char*)d_ws;
    unsigned short* Wh  = (unsigned short*)(wsb);
    unsigned short* Wl  = (unsigned short*)(wsb + 32768);
    unsigned short* Wch = (unsigned short*)(wsb + 65536);
    unsigned short* Wcl = (unsigned short*)(wsb + 73728);
    float* bpre         = (float*)(wsb + 81920);
    unsigned short* hsb = (unsigned short*)(wsb + 98304);
    float* pooled       = (float*)(wsb + 33652736);

    prep_kernel<<<1, 256, 0, stream>>>(W_in, b_in, W_ih, b_ih, b_hh, W_hh,
                                       Wh, Wl, Wch, Wcl, bpre);
    rnn_kernel<<<32, 256, 0, stream>>>(x, h0, Wh, Wl, Wch, Wcl, bpre, hsb);
    pool_kernel<<<2048, 256, 0, stream>>>(hsb, pooled);
    out_kernel<<<512, 256, 0, stream>>>(pooled, W_out, b_out, out);
}

// Round 10
// 227.067 us; speedup vs baseline: 1.5106x; 1.2493x over previous
//
#include <hip/hip_runtime.h>

#define L 256
#define BATCH 512
#define CIN 32
#define HIDN 128
#define OUTN 512

typedef _Float16 f16x8 __attribute__((ext_vector_type(8)));
typedef float f32x4 __attribute__((ext_vector_type(4)));

#define MFMA16(a, b, c) __builtin_amdgcn_mfma_f32_16x16x32_f16(a, b, c, 0, 0, 0)

static __device__ __forceinline__ unsigned short f16b(_Float16 h) {
    unsigned short u; __builtin_memcpy(&u, &h, 2); return u;
}

// ws layout (bytes):
//   Wh   @ 0      (32768)  fp16 hi of W_hh [j][k]
//   Wl   @ 32768  (32768)  fp16 lo residual (W to 22 bits; systematic error)
//   Wch  @ 65536  (8192)   fp16 hi of Wc = W_ih@W_in [j][c]
//   Wcl  @ 73728  (8192)
//   bpre @ 81920  (512)    fp32 b_ih + b_hh + W_ih@b_in
//   hs   @ 98304  (33554432) fp16 hs[t*65536 + b*128 + j]

__global__ __launch_bounds__(256) void prep_kernel(
    const float* __restrict__ W_in, const float* __restrict__ b_in,
    const float* __restrict__ W_ih, const float* __restrict__ b_ih,
    const float* __restrict__ b_hh, const float* __restrict__ Whh,
    unsigned short* __restrict__ Wh, unsigned short* __restrict__ Wl,
    unsigned short* __restrict__ Wch, unsigned short* __restrict__ Wcl,
    float* __restrict__ bpre)
{
    const int tid = threadIdx.x;
    __shared__ float win[64 * CIN];
    for (int i = tid; i < 64 * CIN; i += 256) win[i] = W_in[i];
    __syncthreads();
    if (tid < 128) {
        const int j = tid;
        float acc[CIN];
#pragma unroll
        for (int c = 0; c < CIN; ++c) acc[c] = 0.f;
        float bs = b_ih[j] + b_hh[j];
        for (int m = 0; m < 64; ++m) {
            float w = W_ih[j * 64 + m];
            bs += w * b_in[m];
#pragma unroll
            for (int c = 0; c < CIN; ++c) acc[c] += w * win[m * CIN + c];
        }
        bpre[j] = bs;
#pragma unroll
        for (int c = 0; c < CIN; ++c) {
            _Float16 h = (_Float16)acc[c];
            _Float16 l = (_Float16)(acc[c] - (float)h);
            Wch[j * CIN + c] = f16b(h);
            Wcl[j * CIN + c] = f16b(l);
        }
    } else {
        const int j = tid - 128;
        for (int k = 0; k < HIDN; k += 4) {
            float4 v = *(const float4*)(Whh + j * HIDN + k);
            float vv[4] = {v.x, v.y, v.z, v.w};
#pragma unroll
            for (int u = 0; u < 4; ++u) {
                _Float16 h = (_Float16)vv[u];
                _Float16 l = (_Float16)(vv[u] - (float)h);
                Wh[j * HIDN + k + u] = f16b(h);
                Wl[j * HIDN + k + u] = f16b(l);
            }
        }
    }
}

// MFMA RNN, fp16 2-term split. 32 blocks (16 batch rows) x 512 thr (8 waves,
// 2/SIMD). Wave w owns j-slice [16w,16w+16) = ONE 16x16 tile, full K=128.
// R9 post-mortem: at 1 wave/SIMD the serial path (ds_read latency -> 5-deep
// MFMA chain -> exp epilogue -> barrier) was raw-exposed (1294 cyc/step).
// 8-wave split halves per-wave work and doubles waves/SIMD so the stalls of
// one wave are filled by the other. Per wave per step: 10 MFMA (two 5-chains),
// 4 swizzled b128 h-reads + 1 x-read, half-size epilogue.
__global__ __launch_bounds__(512, 1) void rnn_kernel(
    const float* __restrict__ x, const float* __restrict__ h0,
    const unsigned short* __restrict__ Wh, const unsigned short* __restrict__ Wl,
    const unsigned short* __restrict__ Wch, const unsigned short* __restrict__ Wcl,
    const float* __restrict__ bpre, unsigned short* __restrict__ hs)
{
    const int tid = threadIdx.x;
    const int bb = blockIdx.x;
    const int lane = tid & 63;
    const int w = tid >> 6;       // wave 0..7
    const int n = lane & 15;      // batch col / A row
    const int q = lane >> 4;      // quad

    __shared__ unsigned short hbuf[2][16][HIDN];     // 8 KB, granule swizzle ^(n&7)
    __shared__ unsigned short xc[2][16][16][CIN];    // 32 KB, [chunk][t&15][n][c]

    // A-frags: A[m=lane&15][k=q*8+i]; rows = j = w*16 + n
    f16x8 Ah[4], Al[4], Axh, Axl;
    const int jr = w * 16 + n;
#pragma unroll
    for (int kc = 0; kc < 4; ++kc) {
        Ah[kc] = *(const f16x8*)(Wh + jr * HIDN + kc * 32 + q * 8);
        Al[kc] = *(const f16x8*)(Wl + jr * HIDN + kc * 32 + q * 8);
    }
    Axh = *(const f16x8*)(Wch + jr * CIN + q * 8);
    Axl = *(const f16x8*)(Wcl + jr * CIN + q * 8);
    // C/D rows = q*4+r -> bias for j = w*16 + q*4 + r
    float4 bv = *(const float4*)(bpre + w * 16 + q * 4);
    f32x4 bp = (f32x4){bv.x, bv.y, bv.z, bv.w};

    // ---- h0 -> fp16 plane, dbuf 0 (first 256 threads) ----
    if (tid < 256) {
        const int ni = tid >> 4, gi = tid & 15;
        const float4* src = (const float4*)(h0 + ((size_t)bb * 16 + ni) * HIDN + gi * 8);
        float4 a = src[0], b4 = src[1];
        float vv[8] = {a.x, a.y, a.z, a.w, b4.x, b4.y, b4.z, b4.w};
        unsigned short o[8];
#pragma unroll
        for (int i = 0; i < 8; ++i) o[i] = f16b((_Float16)vv[i]);
        *(uint4*)&hbuf[0][ni][(gi ^ (ni & 7)) * 8] = *(uint4*)o;
    }

    // ---- x chunk staging over 512 threads: i=tid+r*512 -> (nn,cc,tq) ----
    float4 xr[4];
    auto issue_chunk = [&](int ci) {
#pragma unroll
        for (int r = 0; r < 4; ++r) {
            int i = tid + r * 512;
            int nn = i >> 7, cc = (i >> 2) & 31, tq = i & 3;
            xr[r] = *(const float4*)(x + (((size_t)bb * 16 + nn) * CIN + cc) * L + ci * 16 + tq * 4);
        }
    };
    auto write_chunk = [&](int buf) {
#pragma unroll
        for (int r = 0; r < 4; ++r) {
            int i = tid + r * 512;
            int nn = i >> 7, cc = (i >> 2) & 31, tq = i & 3;
            float vv[4] = {xr[r].x, xr[r].y, xr[r].z, xr[r].w};
#pragma unroll
            for (int k = 0; k < 4; ++k)
                xc[buf][tq * 4 + k][nn][cc] = f16b((_Float16)vv[k]);
        }
    };

    issue_chunk(0);
    write_chunk(0);
    issue_chunk(1);
    __syncthreads();

    unsigned short* hsp = hs + ((size_t)bb * 16 + n) * HIDN + w * 16 + q * 4;

    for (int t = 0; t < L; ++t) {
        const int p = t & 1;
        const int cb = (t >> 4) & 1, tt = t & 15;

        f16x8 Bh[4];
#pragma unroll
        for (int kc = 0; kc < 4; ++kc)
            Bh[kc] = *(const f16x8*)&hbuf[p][n][((4 * kc + q) ^ (n & 7)) * 8];
        f16x8 xB = *(const f16x8*)&xc[cb][tt][n][q * 8];

        // 10 MFMA, two independent 5-chains
        f32x4 aH = bp;
        f32x4 aL = (f32x4){0.f, 0.f, 0.f, 0.f};
#pragma unroll
        for (int kc = 0; kc < 4; ++kc) {
            aH = MFMA16(Ah[kc], Bh[kc], aH);
            aL = MFMA16(Al[kc], Bh[kc], aL);
        }
        aH = MFMA16(Axh, xB, aH);
        aL = MFMA16(Axl, xB, aL);

        if (tt == 15 && t < L - 16) {
            write_chunk(cb ^ 1);
            if (t < L - 32) issue_chunk((t >> 4) + 2);
        }

        f32x4 acc = aH + aL;
        unsigned short o[4];
#pragma unroll
        for (int r = 0; r < 4; ++r) {
            float e = __expf(2.f * acc[r]);
            float hv = 1.f - 2.f * __builtin_amdgcn_rcpf(e + 1.f);
            o[r] = f16b((_Float16)hv);
        }
        uint2 pk; __builtin_memcpy(&pk, o, 8);
        // j0 = w*16+q*4 -> granule 2w + (q>>1), half (q&1); same ^(n&7) swizzle
        const int G = (w * 2 + (q >> 1)) ^ (n & 7);
        *(uint2*)&hbuf[p ^ 1][n][G * 8 + (q & 1) * 4] = pk;
        *(uint2*)(hsp + (size_t)t * (BATCH * HIDN)) = pk;

        asm volatile("" ::: "memory");
        __builtin_amdgcn_s_waitcnt(0xC07F);  // lgkmcnt(0) only; hs stores stay in flight
        __builtin_amdgcn_s_barrier();
        asm volatile("" ::: "memory");
    }
}

// Fused upsample(16->32, align_corners) + hardswish + mean + out-GEMM.
// 512 blocks (1 per batch row), 256 threads. hs row staged once in 64 KB LDS;
// bilinear as per-oy row-blend (16) + 32 col-blends (weights compile-time).
__global__ __launch_bounds__(256) void pool_out_kernel(
    const unsigned short* __restrict__ hs, const float* __restrict__ W_out,
    const float* __restrict__ b_out, float* __restrict__ out)
{
    const int b = blockIdx.x, tid = threadIdx.x;
    __shared__ unsigned short m[L][HIDN];   // 64 KB fp16
    __shared__ float ps[2][HIDN];
    __shared__ float pooled_s[HIDN];

#pragma unroll
    for (int it = 0; it < 16; ++it) {
        int i = tid + it * 256;             // uint4 granule = 8 fp16
        int t = i >> 4, g = i & 15;
        *(uint4*)&m[t][g * 8] =
            *(const uint4*)(hs + (size_t)t * (BATCH * HIDN) + b * HIDN + g * 8);
    }
    __syncthreads();

    const int jo = tid & 127, sub = tid >> 7;
    float acc = 0.f;
    for (int oy = sub * 16; oy < sub * 16 + 16; ++oy) {
        float ysf = oy * (15.f / 31.f);
        int y0 = (int)ysf; float wy = ysf - (float)y0; int y1 = min(y0 + 1, 15);
        float rb[16];
#pragma unroll
        for (int sx = 0; sx < 16; ++sx) {
            float v0 = (float)*(const _Float16*)&m[y0 * 16 + sx][jo];
            float v1 = (float)*(const _Float16*)&m[y1 * 16 + sx][jo];
            rb[sx] = v0 + wy * (v1 - v0);
        }
#pragma unroll
        for (int ox = 0; ox < 32; ++ox) {
            float xsf = ox * (15.f / 31.f);
            int x0 = (int)xsf; float wx = xsf - (float)x0; int x1 = min(x0 + 1, 15);
            float v = rb[x0] + wx * (rb[x1] - rb[x0]);
            float t6 = fminf(fmaxf(v + 3.f, 0.f), 6.f);
            acc += v * t6;
        }
    }
    ps[sub][jo] = acc;
    __syncthreads();
    if (tid < 128) pooled_s[tid] = (ps[0][tid] + ps[1][tid]) * (1.f / 6144.f);
    __syncthreads();

    for (int o = tid; o < OUTN; o += 256) {
        float a = b_out[o];
#pragma unroll 8
        for (int k = 0; k < HIDN; k += 4) {
            float4 wv = *(const float4*)(W_out + o * HIDN + k);
            float4 pv = *(const float4*)&pooled_s[k];   // broadcast b128
            a += wv.x * pv.x + wv.y * pv.y + wv.z * pv.z + wv.w * pv.w;
        }
        out[b * OUTN + o] = a;
    }
}

extern "C" void kernel_launch(void* const* d_in, const int* in_sizes, int n_in,
                              void* d_out, int out_size, void* d_ws, size_t ws_size,
                              hipStream_t stream)
{
    const float* x     = (const float*)d_in[0];
    const float* h0    = (const float*)d_in[1];
    const float* W_in  = (const float*)d_in[2];
    const float* b_in  = (const float*)d_in[3];
    const float* W_ih  = (const float*)d_in[4];
    const float* b_ih  = (const float*)d_in[5];
    const float* W_hh  = (const float*)d_in[6];
    const float* b_hh  = (const float*)d_in[7];
    const float* W_out = (const float*)d_in[8];
    const float* b_out = (const float*)d_in[9];
    float* out = (float*)d_out;

    char* wsb = (char*)d_ws;
    unsigned short* Wh  = (unsigned short*)(wsb);
    unsigned short* Wl  = (unsigned short*)(wsb + 32768);
    unsigned short* Wch = (unsigned short*)(wsb + 65536);
    unsigned short* Wcl = (unsigned short*)(wsb + 73728);
    float* bpre         = (float*)(wsb + 81920);
    unsigned short* hsb = (unsigned short*)(wsb + 98304);

    prep_kernel<<<1, 256, 0, stream>>>(W_in, b_in, W_ih, b_ih, b_hh, W_hh,
                                       Wh, Wl, Wch, Wcl, bpre);
    rnn_kernel<<<32, 512, 0, stream>>>(x, h0, Wh, Wl, Wch, Wcl, bpre, hsb);
    pool_out_kernel<<<512, 256, 0, stream>>>(hsb, W_out, b_out, out);
}